// Round 8
// baseline (144.164 us; speedup 1.0000x reference)
//
#include <hip/hip_runtime.h>

// SSIM loss over [8,8,3,256,256] fp32.
// Packed-FP16 convolutions (v_pk_fma_f16), fp32 epilogue.
// R13: full unroll (ring->SSA, rule-#20 fix) + sum/diff channels. 60.6us.
// R14 REGRESSION: DPP shifts (wait-state hazards; bpermute on the
//      concurrent DS pipe is the keeper).
// R15: branchless clamped loads + 2-deep prefetch. band 52.7us, busy 65%.
// R16: LDS halo-sharing (cooperative stage, 26 rows/block, s/d packed
//      fp16). FETCH 104->78MB (dedup confirmed) but band 54.9us, busy 56:
//      the 11x ds_read_b128 per output row put lgkmcnt waits on the
//      critical path -- traded VALU for DS-latency stalls. Occupancy
//      pinned ~50% (4 blocks/CU) despite 26.5KB LDS -> granularity.
// R17: HYBRID. Keep R16's cooperative dedup'd staging (what gets loaded);
//      restore R13/R15's register-ring vertical (how it's read). Per wave:
//      10 ds_read_b128 ring preload + 1/row = 14 reads/wave vs 44.
//      Vertical is pure VALU from registers again. Horizontal unchanged
//      (bpermute keeper). Ring ~44 VGPR, full-unroll SSA (R13-proven).
// R9 scar: cvt_pkrtz returns half2 directly -- bit-cast, don't assign to v2f.

typedef _Float16 h2 __attribute__((ext_vector_type(2)));
typedef __fp16 fp16v2 __attribute__((ext_vector_type(2)));

#define WSZ 11
#define RAD 5
#define IMH 256
#define IMW 256
#define BROWS 16                     // output rows per block
#define HROWS (BROWS + 2 * RAD)      // 26 staged rows
#define NBANDS (IMH / BROWS)         // 16
#define NPLANES 192                  // 8*8*3
#define NGRID (NPLANES * NBANDS)     // 3072 blocks
#define WPB 4                        // waves per block
#define RPW (BROWS / WPB)            // 4 output rows per wave
#define NPIXF (192.0f * 256.0f * 256.0f)

// Gaussian(sigma=1.5, ws=11) weights, normalized.
#define GW0 0.001028381f
#define GW1 0.007598770f
#define GW2 0.036000770f
#define GW3 0.109360600f
#define GW4 0.213005700f
#define GW5 0.266011790f

// ---- packed fp16 ops (full-rate VOP3P) ----
__device__ __forceinline__ h2 pk_fma16(h2 a, h2 b, h2 c) {
    h2 d;
    asm("v_pk_fma_f16 %0, %1, %2, %3" : "=v"(d) : "v"(a), "v"(b), "v"(c));
    return d;
}
__device__ __forceinline__ h2 pk_mul16(h2 a, h2 b) {
    h2 d;
    asm("v_pk_mul_f16 %0, %1, %2" : "=v"(d) : "v"(a), "v"(b));
    return d;
}
__device__ __forceinline__ h2 pk_add16(h2 a, h2 b) {
    h2 d;
    asm("v_pk_add_f16 %0, %1, %2" : "=v"(d) : "v"(a), "v"(b));
    return d;
}
__device__ __forceinline__ h2 pk_min16(h2 a, h2 b) {
    h2 d;
    asm("v_pk_min_f16 %0, %1, %2" : "=v"(d) : "v"(a), "v"(b));
    return d;
}
__device__ __forceinline__ h2 pk_max16(h2 a, h2 b) {
    h2 d;
    asm("v_pk_max_f16 %0, %1, %2" : "=v"(d) : "v"(a), "v"(b));
    return d;
}

union H2U { h2 h; unsigned u; };
__device__ __forceinline__ unsigned h2u(h2 v) { H2U x; x.h = v; return x.u; }
__device__ __forceinline__ h2 u2h(unsigned v) { H2U x; x.u = v; return x.h; }

// raw lane gather: src lane index precomputed (byte addr = lane*4)
__device__ __forceinline__ h2 bperm(int idx, h2 v) {
    return u2h((unsigned)__builtin_amdgcn_ds_bpermute(idx, (int)h2u(v)));
}
// {lo.h1, hi.h0}
__device__ __forceinline__ h2 albt(h2 hi, h2 lo) {
    return u2h(__builtin_amdgcn_alignbit(h2u(hi), h2u(lo), 16));
}

__device__ __forceinline__ h2 splat16(float s) {
    _Float16 t = (_Float16)s;
    return (h2){t, t};
}
__device__ __forceinline__ h2 zero16() { return (h2){(_Float16)0, (_Float16)0}; }

// pack two floats to half2 (v_cvt_pkrtz_f16_f32), clamp to [0,1] in fp16
// (equivalent to fp32-clamp-then-cvt for this data; 3 ops vs 5).
__device__ __forceinline__ h2 clip_pack(float a, float b, h2 Z, h2 O) {
    fp16v2 r = __builtin_amdgcn_cvt_pkrtz(a, b);
    h2 v = __builtin_bit_cast(h2, r);
    return pk_min16(pk_max16(v, Z), O);
}

__global__ __launch_bounds__(256, 4) void ssim_band_kernel(
    const float* __restrict__ pred,
    const float* __restrict__ targ,
    float* __restrict__ partial)
{
    const int tid = threadIdx.x;
    const int lane = tid & 63;
    const int wid = tid >> 6;              // 4 waves per block
    const int blk = blockIdx.x;
    const int plane = blk >> 4;            // 16 bands per plane
    const int band = blk & 15;
    const int r0 = band * BROWS;

    const float4* __restrict__ pp =
        (const float4*)(pred + (size_t)plane * (IMH * IMW));
    const float4* __restrict__ tp =
        (const float4*)(targ + (size_t)plane * (IMH * IMW));

    const h2 W0 = splat16(GW0), W1 = splat16(GW1), W2 = splat16(GW2),
             W3 = splat16(GW3), W4 = splat16(GW4), W5 = splat16(GW5);
    const h2 wv16[WSZ] = {W0, W1, W2, W3, W4, W5, W4, W3, W2, W1, W0};
    const h2 M2 = splat16(-2.0f);
    const h2 Z16 = zero16();
    const h2 O16 = splat16(1.0f);

    // Shared halo: 26 rows x 64 lanes x 16B = 26KB.
    // Each uint4 = {s01, d01, s23, d23} packed fp16 for 4 columns.
    __shared__ uint4 lds[HROWS * 64];
    __shared__ float wsum[WPB];

    // ---- Cooperative stage: 26 halo rows, once per block. ----
    // Branchless: clamped row address; OOB rows written as zeros (== the
    // reference's zero-padding).
    for (int j = wid; j < HROWS; j += WPB) {
        const int r = r0 - RAD + j;
        const int rc = min(max(r, 0), IMH - 1);
        const bool oob = (r < 0) | (r >= IMH);
        const float4 a = pp[rc * 64 + lane];
        const float4 c = tp[rc * 64 + lane];
        const h2 x0 = clip_pack(a.x, a.y, Z16, O16);
        const h2 x1 = clip_pack(a.z, a.w, Z16, O16);
        const h2 y0 = clip_pack(c.x, c.y, Z16, O16);
        const h2 y1 = clip_pack(c.z, c.w, Z16, O16);
        const h2 s0 = pk_add16(x0, y0);
        const h2 s1 = pk_add16(x1, y1);
        const h2 d0 = pk_fma16(M2, y0, s0);   // s - 2y = x - y
        const h2 d1 = pk_fma16(M2, y1, s1);
        uint4 w;
        w.x = oob ? 0u : h2u(s0);
        w.y = oob ? 0u : h2u(d0);
        w.z = oob ? 0u : h2u(s1);
        w.w = oob ? 0u : h2u(d1);
        lds[j * 64 + lane] = w;
    }
    __syncthreads();

    // Hoisted shuffle machinery: 4 index vectors + 4 edge predicates.
    const int iu1 = (lane - 1) << 2;
    const int iu2 = (lane - 2) << 2;
    const int id1 = (lane + 1) << 2;
    const int id2 = (lane + 2) << 2;
    const bool mu1 = lane >= 1;
    const bool mu2 = lane >= 2;
    const bool md1 = lane <= 62;
    const bool md2 = lane <= 61;

    // Register ring: 11 rows x {s01,d01,s23,d23}. Fully-unrolled modular
    // indexing -> SSA (rule-#20). Output row i uses LDS rows jb0+i..jb0+i+10.
    const int jb0 = wid * RPW;
    h2 ring[WSZ][4];

    // Preload ring rows 0..9 from LDS (10 x ds_read_b128).
#pragma unroll
    for (int j = 0; j < 10; ++j) {
        const uint4 v = lds[(jb0 + j) * 64 + lane];
        ring[j][0] = u2h(v.x); ring[j][1] = u2h(v.y);
        ring[j][2] = u2h(v.z); ring[j][3] = u2h(v.w);
    }

    const float C1 = 1e-4f, C2 = 9e-4f;
    float lsum = 0.f;

    // ---- Each wave computes RPW=4 output rows. ----
#pragma unroll
    for (int i = 0; i < RPW; ++i) {
        // Read the one new row into the incoming slot (1 x ds_read_b128).
        const int sIn = (i + 10) % WSZ;
        {
            const uint4 v = lds[(jb0 + 10 + i) * 64 + lane];
            ring[sIn][0] = u2h(v.x); ring[sIn][1] = u2h(v.y);
            ring[sIn][2] = u2h(v.z); ring[sIn][3] = u2h(v.w);
        }

        // Vertical pass from registers: 4 channels {s,d,s^2,d^2} x 2 pairs.
        h2 vd[4][2];
#pragma unroll
        for (int p = 0; p < 2; ++p) {
            vd[0][p] = zero16(); vd[1][p] = zero16();
            vd[2][p] = zero16(); vd[3][p] = zero16();
        }
#pragma unroll
        for (int k = 0; k < WSZ; ++k) {
            const int sl = (i + k) % WSZ;    // compile-time after unroll
            const h2 wk = wv16[k];
            const h2 sA = ring[sl][0], dA = ring[sl][1];
            const h2 sB = ring[sl][2], dB = ring[sl][3];
            h2 ws = pk_mul16(wk, sA);
            h2 wd = pk_mul16(wk, dA);
            vd[0][0] = pk_add16(vd[0][0], ws);
            vd[1][0] = pk_add16(vd[1][0], wd);
            vd[2][0] = pk_fma16(ws, sA, vd[2][0]);
            vd[3][0] = pk_fma16(wd, dA, vd[3][0]);
            ws = pk_mul16(wk, sB);
            wd = pk_mul16(wk, dB);
            vd[0][1] = pk_add16(vd[0][1], ws);
            vd[1][1] = pk_add16(vd[1][1], wd);
            vd[2][1] = pk_fma16(ws, sB, vd[2][1]);
            vd[3][1] = pk_fma16(wd, dB, vd[3][1]);
        }

        // Horizontal pass per channel (keeper): 6 bpermutes (DS pipe,
        // overlaps VALU) + 6 edge guards + 7 alignbits + 22 pk ops.
        h2 hf[4][2];
#pragma unroll
        for (int ch = 0; ch < 4; ++ch) {
            const h2 H0 = vd[ch][0], H1 = vd[ch][1];
            h2 Gm3 = bperm(iu2, H1);      // {v-1, v0}
            h2 Gm2 = bperm(iu1, H0);      // {v1, v2}
            h2 Gm1 = bperm(iu1, H1);      // {v3, v4}
            h2 G2  = bperm(id1, H0);      // {v9, v10}
            h2 G3  = bperm(id1, H1);      // {v11, v12}
            h2 G4  = bperm(id2, H0);      // {v13, v14}
            Gm3 = mu2 ? Gm3 : zero16();
            Gm2 = mu1 ? Gm2 : zero16();
            Gm1 = mu1 ? Gm1 : zero16();
            G2  = md1 ? G2  : zero16();
            G3  = md1 ? G3  : zero16();
            G4  = md2 ? G4  : zero16();
            // Consecutive pairs P_k = {v[k], v[k+1]}.
            const h2 P0  = albt(Gm2, Gm3);
            const h2 P1  = Gm2;
            const h2 P2  = albt(Gm1, Gm2);
            const h2 P3  = Gm1;
            const h2 P4  = albt(H0, Gm1);
            const h2 P5  = H0;
            const h2 P6  = albt(H1, H0);
            const h2 P7  = H1;
            const h2 P8  = albt(G2, H1);
            const h2 P9  = G2;
            const h2 P10 = albt(G3, G2);
            const h2 P11 = G3;
            const h2 P12 = albt(G4, G3);
            // out pair {c0,c1} = sum_k w[k] * P_k
            h2 a0 = pk_mul16(W0, P0);
            a0 = pk_fma16(W1, P1, a0);
            a0 = pk_fma16(W2, P2, a0);
            a0 = pk_fma16(W3, P3, a0);
            a0 = pk_fma16(W4, P4, a0);
            a0 = pk_fma16(W5, P5, a0);
            a0 = pk_fma16(W4, P6, a0);
            a0 = pk_fma16(W3, P7, a0);
            a0 = pk_fma16(W2, P8, a0);
            a0 = pk_fma16(W1, P9, a0);
            a0 = pk_fma16(W0, P10, a0);
            // out pair {c2,c3} = sum_k w[k] * P_{k+2}
            h2 a1 = pk_mul16(W0, P2);
            a1 = pk_fma16(W1, P3, a1);
            a1 = pk_fma16(W2, P4, a1);
            a1 = pk_fma16(W3, P5, a1);
            a1 = pk_fma16(W4, P6, a1);
            a1 = pk_fma16(W5, P7, a1);
            a1 = pk_fma16(W4, P8, a1);
            a1 = pk_fma16(W3, P9, a1);
            a1 = pk_fma16(W2, P10, a1);
            a1 = pk_fma16(W1, P11, a1);
            a1 = pk_fma16(W0, P12, a1);
            hf[ch][0] = a0;
            hf[ch][1] = a1;
        }

        // SSIM epilogue in fp32 from sum/diff moments.
        // ms=G*s, md=G*d, Ss=G*s^2, Sd=G*d^2.
#pragma unroll
        for (int p = 0; p < 2; ++p) {
#pragma unroll
            for (int e = 0; e < 2; ++e) {
                const float ms = (float)hf[0][p][e];
                const float md = (float)hf[1][p][e];
                const float Ss = (float)hf[2][p][e];
                const float Sd = (float)hf[3][p][e];
                const float P = ms * ms, Q = md * md;
                const float mxy2 = 0.5f * (P - Q);          // 2*mx*my
                const float m2s  = 0.5f * (P + Q);          // mx^2+my^2
                const float Ssum = 0.5f * (Ss + Sd);        // Sxx+Syy
                const float ssum = fmaxf(Ssum - m2s, 0.f);  // vx+vy (joint clamp)
                const float sxy2 = fmaf(0.5f, Ss - Sd, -mxy2); // 2*sigma_xy
                const float num = (mxy2 + C1) * (sxy2 + C2);
                const float den = fmaf(m2s + C1, ssum + C2, 1e-8f);
                lsum += num * __builtin_amdgcn_rcpf(den);
            }
        }
        // No ring shift: modular indices rotate statically (unrolled).
    }

    // Wave reduction (64 lanes), then 4-wave LDS combine -> one store/block.
#pragma unroll
    for (int off = 32; off > 0; off >>= 1)
        lsum += __shfl_xor(lsum, off, 64);

    if (lane == 0) wsum[wid] = lsum;
    __syncthreads();
    if (tid == 0)
        partial[blk] = wsum[0] + wsum[1] + wsum[2] + wsum[3];
}

__global__ __launch_bounds__(256) void ssim_finalize(
    const float* __restrict__ partial,
    float* __restrict__ out)
{
    __shared__ float wsum[4];
    const int t = threadIdx.x;  // 256 threads
    float s = 0.f;
    for (int i = t; i < NGRID; i += 256) s += partial[i];
#pragma unroll
    for (int off = 32; off > 0; off >>= 1)
        s += __shfl_xor(s, off, 64);
    const int lane = t & 63, wv = t >> 6;
    if (lane == 0) wsum[wv] = s;
    __syncthreads();
    if (t == 0)
        out[0] = 1.0f - (wsum[0] + wsum[1] + wsum[2] + wsum[3]) / NPIXF;
}

extern "C" void kernel_launch(void* const* d_in, const int* in_sizes, int n_in,
                              void* d_out, int out_size, void* d_ws, size_t ws_size,
                              hipStream_t stream) {
    const float* pred = (const float*)d_in[0];
    const float* targ = (const float*)d_in[1];
    float* out = (float*)d_out;
    float* part = (float*)d_ws;    // 3072 floats = 12 KB scratch

    ssim_band_kernel<<<NGRID, 256, 0, stream>>>(pred, targ, part);
    ssim_finalize<<<1, 256, 0, stream>>>(part, out);
}

// Round 10
// 127.987 us; speedup vs baseline: 1.1264x; 1.1264x over previous
//
#include <hip/hip_runtime.h>

// SSIM loss over [8,8,3,256,256] fp32.
// R13-R17: VALU-issue-bound at ~21M packed-fp16 instrs, 140-144us total,
//   MfmaUtil 0.0 all session. R18: MFMA rewrite of both separable conv
//   passes (banded Gaussian weight matrix, one weight fragment serves both
//   passes). FAILED correctness (absmax 0.19, per-pixel up to ~468 =
//   negative-variance signature -> spatially mis-routed conv windows).
//   Root-cause hypothesis: used LEGACY mfma_f32_16x16x16f16, which is NOT
//   in the gfx950 HW-verified intrinsic list and whose C/D layout is
//   unverified on this chip.
// R19: switch to __builtin_amdgcn_mfma_f32_16x16x32_f16 -- the gfx950
//   instruction with m89/m91-verified C/D layout (col=lane&15,
//   row=4*(lane>>4)+reg; dtype-independent per m121-m128) and A/B k-order
//   corroborated by m162's tr-read formula (k = 4*(lane>>4)+j per 16-k
//   block; 8-elem frag = [block0 | block1]). K=32 matches our padded K
//   exactly -> ONE mfma per conv per channel (was 2). All LDS layouts
//   unchanged from R18.
//   PLAN-B if still failing with absmax ~0.1-0.5: flip V-write mapping to
//   row=lane&15, col=4g+r (transposed D). If absmax ~1e-3..1e-2: layout
//   right, precision marginal -> store V planes f32.
// Pipeline per block (16 rows x 256 cols, 4 waves):
//   stage s,d col-major planes (stride 72B; v_perm repack; b64 writes)
//   -> barrier -> vertical MFMAs (squares via pk_mul on B-frags; f32 accum)
//   -> barrier -> write V planes row-major f16 into dead input region
//   (+zero pads = conv zero-padding) -> barrier -> horizontal MFMAs ->
//   f32 epilogue from accumulators.
// R9 scar: cvt_pkrtz returns half2 directly -- bit-cast.
// Rule-20: all arrays fully unrolled / compile-time indexed.

typedef _Float16 h2 __attribute__((ext_vector_type(2)));
typedef _Float16 half4 __attribute__((ext_vector_type(4)));
typedef _Float16 half8 __attribute__((ext_vector_type(8)));
typedef float f32x4 __attribute__((ext_vector_type(4)));
typedef __fp16 fp16v2 __attribute__((ext_vector_type(2)));

#define WSZ 11
#define RAD 5
#define IMH 256
#define IMW 256
#define BROWS 16                     // output rows per block
#define NBANDS (IMH / BROWS)         // 16
#define NPLANES 192                  // 8*8*3
#define NGRID (NPLANES * NBANDS)     // 3072 blocks
#define WPB 4                        // waves per block
#define NPIXF (192.0f * 256.0f * 256.0f)

// Input planes (s,d): col-major [256 col][36 k-slot] f16, stride 72B.
#define CSTRIDE 72
#define INPLANE (256 * CSTRIDE)      // 18432 B per channel
// V planes (4 ch): row-major [16 row][276 col] f16, stride 552B.
#define VROWSTRIDE 552
#define VPLANE (16 * VROWSTRIDE)     // 8832 B per channel
#define SMEM_BYTES 36864             // max(2*INPLANE, 4*VPLANE)

// ---- packed fp16 ops ----
__device__ __forceinline__ h2 pk_fma16(h2 a, h2 b, h2 c) {
    h2 d;
    asm("v_pk_fma_f16 %0, %1, %2, %3" : "=v"(d) : "v"(a), "v"(b), "v"(c));
    return d;
}
__device__ __forceinline__ h2 pk_mul16(h2 a, h2 b) {
    h2 d;
    asm("v_pk_mul_f16 %0, %1, %2" : "=v"(d) : "v"(a), "v"(b));
    return d;
}
__device__ __forceinline__ h2 pk_add16(h2 a, h2 b) {
    h2 d;
    asm("v_pk_add_f16 %0, %1, %2" : "=v"(d) : "v"(a), "v"(b));
    return d;
}
__device__ __forceinline__ h2 pk_min16(h2 a, h2 b) {
    h2 d;
    asm("v_pk_min_f16 %0, %1, %2" : "=v"(d) : "v"(a), "v"(b));
    return d;
}
__device__ __forceinline__ h2 pk_max16(h2 a, h2 b) {
    h2 d;
    asm("v_pk_max_f16 %0, %1, %2" : "=v"(d) : "v"(a), "v"(b));
    return d;
}

union H2U { h2 h; unsigned u; };
__device__ __forceinline__ unsigned h2u(h2 v) { H2U x; x.h = v; return x.u; }

__device__ __forceinline__ h2 splat16(float s) {
    _Float16 t = (_Float16)s;
    return (h2){t, t};
}
__device__ __forceinline__ h2 zero16() { return (h2){(_Float16)0, (_Float16)0}; }

// clip to [0,1] in fp16 after pack (range-equivalent for this data).
__device__ __forceinline__ h2 clip_pack(float a, float b, h2 Z, h2 O) {
    fp16v2 r = __builtin_amdgcn_cvt_pkrtz(a, b);
    h2 v = __builtin_bit_cast(h2, r);
    return pk_min16(pk_max16(v, Z), O);
}

// v_perm_b32 pair builders: {a.f16[0], b.f16[0]} and {a.f16[1], b.f16[1]}.
// llvm.amdgcn.perm(src0=hi bytes 4-7, src1=lo bytes 0-3, sel).
__device__ __forceinline__ unsigned lo_pair(h2 a, h2 b) {
    return __builtin_amdgcn_perm(h2u(b), h2u(a), 0x05040100u);
}
__device__ __forceinline__ unsigned hi_pair(h2 a, h2 b) {
    return __builtin_amdgcn_perm(h2u(b), h2u(a), 0x07060302u);
}

// gfx950 f16 MFMA, K=32, HW-verified layouts (m89 family).
__device__ __forceinline__ f32x4 mfma32(half8 a, half8 b, f32x4 c) {
    return __builtin_amdgcn_mfma_f32_16x16x32_f16(a, b, c, 0, 0, 0);
}

__device__ __forceinline__ half8 cat8(half4 lo, half4 hi) {
    half8 r;
    r[0] = lo[0]; r[1] = lo[1]; r[2] = lo[2]; r[3] = lo[3];
    r[4] = hi[0]; r[5] = hi[1]; r[6] = hi[2]; r[7] = hi[3];
    return r;
}

// elementwise square of a half4 (2x v_pk_mul_f16)
__device__ __forceinline__ half4 sq4(half4 v) {
    union { half4 v4; h2 h[2]; } u, r;
    u.v4 = v;
    r.h[0] = pk_mul16(u.h[0], u.h[0]);
    r.h[1] = pk_mul16(u.h[1], u.h[1]);
    return r.v4;
}

__global__ __launch_bounds__(256, 4) void ssim_band_kernel(
    const float* __restrict__ pred,
    const float* __restrict__ targ,
    float* __restrict__ partial)
{
    const int tid = threadIdx.x;
    const int lane = tid & 63;
    const int wid = tid >> 6;              // 4 waves per block
    const int g = lane >> 4;               // MFMA k-quad group
    const int m = lane & 15;               // MFMA row/col index
    const int blk = blockIdx.x;
    const int plane = blk >> 4;            // 16 bands per plane
    const int band = blk & 15;
    const int r0 = band * BROWS;

    const float4* __restrict__ pp =
        (const float4*)(pred + (size_t)plane * (IMH * IMW));
    const float4* __restrict__ tp =
        (const float4*)(targ + (size_t)plane * (IMH * IMW));

    __shared__ __align__(16) char smem[SMEM_BYTES];
    __shared__ float wsum[WPB];

    const h2 M2 = splat16(-2.0f);
    const h2 Z16 = zero16();
    const h2 O16 = splat16(1.0f);

    // ---- Weight fragment (shared by both passes): w = gw[k - m] ----
    // elem e: k = (e>>2)*16 + 4*g + (e&3)  [m162-corroborated k-order]
    // gw[d] = 0.266011790 * exp(-(d-5)^2/4.5), d in [0,10], else 0.
    half8 wf;
    {
#pragma unroll
        for (int e = 0; e < 8; ++e) {
            const int k = (e >> 2) * 16 + 4 * g + (e & 3);
            const int dd = k - m;
            const float t = (float)(dd - 5);
            float w = 0.266011790f * exp2f(t * t * -0.32059890f);
            if (dd < 0 || dd > 10) w = 0.f;
            wf[e] = (_Float16)w;
        }
    }

    // ---- Stage: s,d planes col-major [col][k], k = 0..31 (rows r0-5..r0+26).
    // Wave w owns k-quads {8w..8w+3}, {8w+4..8w+7}. Lane owns cols 4l..4l+3.
#pragma unroll
    for (int q = 0; q < 2; ++q) {
        const int kq = wid * 8 + q * 4;
        h2 sA[4], sB[4], dA[4], dB[4];
#pragma unroll
        for (int dk = 0; dk < 4; ++dk) {
            const int r = r0 - RAD + kq + dk;
            const int rc = min(max(r, 0), IMH - 1);
            const bool oob = (r < 0) | (r >= IMH);
            const float4 a = pp[rc * 64 + lane];
            const float4 c = tp[rc * 64 + lane];
            const h2 x0 = clip_pack(a.x, a.y, Z16, O16);
            const h2 x1 = clip_pack(a.z, a.w, Z16, O16);
            const h2 y0 = clip_pack(c.x, c.y, Z16, O16);
            const h2 y1 = clip_pack(c.z, c.w, Z16, O16);
            h2 s0 = pk_add16(x0, y0);
            h2 s1 = pk_add16(x1, y1);
            h2 d0 = pk_fma16(M2, y0, s0);   // x - y
            h2 d1 = pk_fma16(M2, y1, s1);
            sA[dk] = oob ? Z16 : s0;
            sB[dk] = oob ? Z16 : s1;
            dA[dk] = oob ? Z16 : d0;
            dB[dk] = oob ? Z16 : d1;
        }
        // Repack rows->col-quads (v_perm) and write b64 per col per channel.
        char* const ws0 = smem + (size_t)(4 * lane) * CSTRIDE + kq * 2;
        char* const wd0 = ws0 + INPLANE;
        uint2 v;
        v.x = lo_pair(sA[0], sA[1]); v.y = lo_pair(sA[2], sA[3]);
        *(uint2*)(ws0 + 0 * CSTRIDE) = v;
        v.x = hi_pair(sA[0], sA[1]); v.y = hi_pair(sA[2], sA[3]);
        *(uint2*)(ws0 + 1 * CSTRIDE) = v;
        v.x = lo_pair(sB[0], sB[1]); v.y = lo_pair(sB[2], sB[3]);
        *(uint2*)(ws0 + 2 * CSTRIDE) = v;
        v.x = hi_pair(sB[0], sB[1]); v.y = hi_pair(sB[2], sB[3]);
        *(uint2*)(ws0 + 3 * CSTRIDE) = v;
        v.x = lo_pair(dA[0], dA[1]); v.y = lo_pair(dA[2], dA[3]);
        *(uint2*)(wd0 + 0 * CSTRIDE) = v;
        v.x = hi_pair(dA[0], dA[1]); v.y = hi_pair(dA[2], dA[3]);
        *(uint2*)(wd0 + 1 * CSTRIDE) = v;
        v.x = lo_pair(dB[0], dB[1]); v.y = lo_pair(dB[2], dB[3]);
        *(uint2*)(wd0 + 2 * CSTRIDE) = v;
        v.x = hi_pair(dB[0], dB[1]); v.y = hi_pair(dB[2], dB[3]);
        *(uint2*)(wd0 + 3 * CSTRIDE) = v;
    }
    __syncthreads();

    // ---- Vertical: D[16x16] = W[16x32] x In[32x16] per tile per channel.
    // Wave owns col-tiles {4*wid .. 4*wid+3}. ONE mfma32 per channel.
    f32x4 Dv[4][4];                       // [tile][ch: s,d,s2,d2]
    const f32x4 z4 = {0.f, 0.f, 0.f, 0.f};
#pragma unroll
    for (int tt = 0; tt < 4; ++tt) {
        const int c0 = (wid * 4 + tt) * 16;
        const char* ps = smem + (size_t)(c0 + m) * CSTRIDE;
        const char* pd = ps + INPLANE;
        const half4 bs_lo = *(const half4*)(ps + 8 * g);
        const half4 bs_hi = *(const half4*)(ps + 32 + 8 * g);
        const half4 bd_lo = *(const half4*)(pd + 8 * g);
        const half4 bd_hi = *(const half4*)(pd + 32 + 8 * g);
        Dv[tt][0] = mfma32(wf, cat8(bs_lo, bs_hi), z4);
        Dv[tt][1] = mfma32(wf, cat8(bd_lo, bd_hi), z4);
        Dv[tt][2] = mfma32(wf, cat8(sq4(bs_lo), sq4(bs_hi)), z4);
        Dv[tt][3] = mfma32(wf, cat8(sq4(bd_lo), sq4(bd_hi)), z4);
    }
    __syncthreads();   // all input-plane reads done; region now reusable

    // ---- Write V planes row-major f16 (reuse smem) + zero pads. ----
    // D layout (m89): lane holds col=m, rows 4g+r. Plane col p = img_col+5.
#pragma unroll
    for (int tt = 0; tt < 4; ++tt) {
        const int c0 = (wid * 4 + tt) * 16;
#pragma unroll
        for (int ch = 0; ch < 4; ++ch) {
            char* vp = smem + ch * VPLANE + (size_t)(5 + c0 + m) * 2;
#pragma unroll
            for (int r = 0; r < 4; ++r) {
                *(__fp16*)(vp + (4 * g + r) * VROWSTRIDE) =
                    (__fp16)Dv[tt][ch][r];
            }
        }
    }
    // Zero pads: p in {0..4} U {261..271}, all 16 rows, 4 channels.
#pragma unroll
    for (int e = 0; e < 4; ++e) {
        const int idx = tid * 4 + e;           // 0..1023
        const int ch = idx >> 8;
        const int rem = idx & 255;
        const int i = rem >> 4;
        const int pc = rem & 15;
        const int p = pc < 5 ? pc : pc + 256;  // 0..4, 261..271
        *(__fp16*)(smem + ch * VPLANE + i * VROWSTRIDE + p * 2) = (__fp16)0.f;
    }
    __syncthreads();

    // ---- Horizontal + epilogue per tile. ----
    const float C1 = 1e-4f, C2 = 9e-4f;
    float lsum = 0.f;
#pragma unroll
    for (int tt = 0; tt < 4; ++tt) {
        const int c0 = (wid * 4 + tt) * 16;
        f32x4 D2[4];
#pragma unroll
        for (int ch = 0; ch < 4; ++ch) {
            const char* vb = smem + ch * VPLANE + (size_t)m * VROWSTRIDE
                           + (size_t)c0 * 2;
            const half4 a_lo = *(const half4*)(vb + 8 * g);
            const half4 a_hi = *(const half4*)(vb + 32 + 8 * g);
            D2[ch] = mfma32(cat8(a_lo, a_hi), wf, z4);
        }
        // Lane: img rows 4g+r, img col c0+m; all 4 channels aligned.
#pragma unroll
        for (int r = 0; r < 4; ++r) {
            const float ms = D2[0][r];
            const float md = D2[1][r];
            const float Ss = D2[2][r];
            const float Sd = D2[3][r];
            const float P = ms * ms, Q = md * md;
            const float mxy2 = 0.5f * (P - Q);            // 2*mx*my
            const float m2s  = 0.5f * (P + Q);            // mx^2+my^2
            const float Ssum = 0.5f * (Ss + Sd);          // Sxx+Syy
            const float ssum = fmaxf(Ssum - m2s, 0.f);    // vx+vy
            const float sxy2 = fmaf(0.5f, Ss - Sd, -mxy2); // 2*sigma_xy
            const float num = (mxy2 + C1) * (sxy2 + C2);
            const float den = fmaf(m2s + C1, ssum + C2, 1e-8f);
            lsum += num * __builtin_amdgcn_rcpf(den);
        }
    }

    // Wave reduction, 4-wave LDS combine, one store per block.
#pragma unroll
    for (int off = 32; off > 0; off >>= 1)
        lsum += __shfl_xor(lsum, off, 64);

    if (lane == 0) wsum[wid] = lsum;
    __syncthreads();
    if (tid == 0)
        partial[blk] = wsum[0] + wsum[1] + wsum[2] + wsum[3];
}

__global__ __launch_bounds__(256) void ssim_finalize(
    const float* __restrict__ partial,
    float* __restrict__ out)
{
    __shared__ float wsum[4];
    const int t = threadIdx.x;  // 256 threads
    float s = 0.f;
    for (int i = t; i < NGRID; i += 256) s += partial[i];
#pragma unroll
    for (int off = 32; off > 0; off >>= 1)
        s += __shfl_xor(s, off, 64);
    const int lane = t & 63, wv = t >> 6;
    if (lane == 0) wsum[wv] = s;
    __syncthreads();
    if (t == 0)
        out[0] = 1.0f - (wsum[0] + wsum[1] + wsum[2] + wsum[3]) / NPIXF;
}

extern "C" void kernel_launch(void* const* d_in, const int* in_sizes, int n_in,
                              void* d_out, int out_size, void* d_ws, size_t ws_size,
                              hipStream_t stream) {
    const float* pred = (const float*)d_in[0];
    const float* targ = (const float*)d_in[1];
    float* out = (float*)d_out;
    float* part = (float*)d_ws;    // 3072 floats = 12 KB scratch

    ssim_band_kernel<<<NGRID, 256, 0, stream>>>(pred, targ, part);
    ssim_finalize<<<1, 256, 0, stream>>>(part, out);
}